// Round 7
// baseline (280.293 us; speedup 1.0000x reference)
//
#include <hip/hip_runtime.h>

#define DH 256
#define LQ 256

typedef __bf16 bf16x8 __attribute__((ext_vector_type(8)));
typedef __bf16 bf16x4 __attribute__((ext_vector_type(4)));
typedef float  f32x4  __attribute__((ext_vector_type(4)));

// ---- stage a 32-row x 256-col panel into LDS bf16 [32][264]; 512 threads ----
__device__ __forceinline__ void stage32f(const float* __restrict__ src, int row0,
                                         __bf16 (*dst)[264], int tid) {
    const int r = tid >> 4;                       // 0..31
    #pragma unroll
    for (int c = 0; c < 2; ++c) {
        const int ch = (tid & 15) + 16 * c;       // 0..31 chunks of 8
        const float* p = src + (row0 + r) * DH + ch * 8;
        float4 a = *(const float4*)p;
        float4 b = *(const float4*)(p + 4);
        bf16x8 v;
        v[0] = (__bf16)a.x; v[1] = (__bf16)a.y; v[2] = (__bf16)a.z; v[3] = (__bf16)a.w;
        v[4] = (__bf16)b.x; v[5] = (__bf16)b.y; v[6] = (__bf16)b.z; v[7] = (__bf16)b.w;
        *(bf16x8*)&dst[r][ch * 8] = v;
    }
}
__device__ __forceinline__ void stage32h(const __bf16* __restrict__ src, int row0,
                                         __bf16 (*dst)[264], int tid) {
    const int r = tid >> 4;
    #pragma unroll
    for (int c = 0; c < 2; ++c) {
        const int ch = (tid & 15) + 16 * c;
        *(bf16x8*)&dst[r][ch * 8] = *(const bf16x8*)&src[(row0 + r) * DH + ch * 8];
    }
}
__device__ __forceinline__ bf16x8 frag(const __bf16 (*m)[264], int r0, int ks, int lane) {
    return *(const bf16x8*)&m[r0 + (lane & 15)][ks * 32 + ((lane >> 4) << 3)];
}

__global__ void k_zero(unsigned* __restrict__ c) {
    if (threadIdx.x < 3) c[threadIdx.x] = 0u;
}

__device__ __forceinline__ void gridbar(unsigned* cnt, unsigned target) {
    __syncthreads();
    __threadfence();
    if (threadIdx.x == 0) {
        __hip_atomic_fetch_add(cnt, 1u, __ATOMIC_ACQ_REL, __HIP_MEMORY_SCOPE_AGENT);
        while (__hip_atomic_load(cnt, __ATOMIC_ACQUIRE, __HIP_MEMORY_SCOPE_AGENT) < target)
            __builtin_amdgcn_s_sleep(2);
    }
    __syncthreads();
    __threadfence();
}

__global__ __launch_bounds__(512) void k_fused(
    const float* __restrict__ X,   const float* __restrict__ rmask,
    const float* __restrict__ Wfc, const float* __restrict__ bfc,
    const float* __restrict__ W1,  const float* __restrict__ W2, const float* __restrict__ b1,
    const float* __restrict__ Wf1, const float* __restrict__ Wf2, const float* __restrict__ bfv,
    __bf16* __restrict__ rep_bf, __bf16* __restrict__ rep_t, __bf16* __restrict__ attn_bf,
    float* __restrict__ Ed_t, float* __restrict__ Eh_t,
    float* __restrict__ out, unsigned* __restrict__ bar)
{
    __shared__ __bf16 PA[32][264];
    __shared__ __bf16 PB[32][264];
    __shared__ __bf16 PC[32][264];
    __shared__ float  EdL[4][256];
    __shared__ float  RpL[4][256];

    const int tid = threadIdx.x, lane = tid & 63, wid = tid >> 6;
    const int mb = blockIdx.x >> 3, nb = blockIdx.x & 7;
    const int r0 = mb * 32, c0 = nb * 32;
    const int wr = ((wid >> 1) & 1) * 16, wc = (wid & 1) * 16;
    const int col = c0 + wc + (lane & 15);
    const int row = r0 + wr + ((lane >> 4) << 2);
    const int b = row >> 8, tok = row & 255;
    const f32x4 z4 = {0.f, 0.f, 0.f, 0.f};

    // ---------------- P1: rep = elu(X @ Wfc^T + bfc) ----------------
    stage32f(X, r0, PA, tid);
    stage32f(Wfc, c0, PB, tid);
    __syncthreads();
    if (wid < 4) {
        f32x4 acc = z4;
        #pragma unroll
        for (int ks = 0; ks < 8; ++ks)
            acc = __builtin_amdgcn_mfma_f32_16x16x32_bf16(frag(PA, wr, ks, lane),
                                                          frag(PB, wc, ks, lane), acc, 0, 0, 0);
        const float bv = bfc[col];
        bf16x4 pk;
        #pragma unroll
        for (int r = 0; r < 4; ++r) {
            float v = acc[r] + bv;
            v = (v > 0.f) ? v : (__expf(v) - 1.f);
            __bf16 h = (__bf16)v;
            rep_bf[(row + r) * DH + col] = h;
            pk[r] = h;
        }
        *(bf16x4*)(rep_t + ((b << 8) + col) * LQ + tok) = pk;
    }
    gridbar(bar + 0, 256);

    // ---------------- P2: Ed = exp(0.4*(rep@W1^T+b1)), Eh = exp(0.4*rep@W2^T) ----------------
    stage32h(rep_bf, r0, PA, tid);
    stage32f(W1, c0, PB, tid);
    stage32f(W2, c0, PC, tid);
    __syncthreads();
    if (wid < 4) {
        f32x4 ad = z4, ah = z4;
        #pragma unroll
        for (int ks = 0; ks < 8; ++ks) {
            bf16x8 a = frag(PA, wr, ks, lane);
            ad = __builtin_amdgcn_mfma_f32_16x16x32_bf16(a, frag(PB, wc, ks, lane), ad, 0, 0, 0);
            ah = __builtin_amdgcn_mfma_f32_16x16x32_bf16(a, frag(PC, wc, ks, lane), ah, 0, 0, 0);
        }
        const float bb = b1[col];
        f32x4 ed, eh;
        #pragma unroll
        for (int r = 0; r < 4; ++r) {
            ed[r] = __expf(0.4f * (ad[r] + bb));   // 2/C = 0.4
            eh[r] = __expf(0.4f * ah[r]);
        }
        *(f32x4*)(Ed_t + ((b << 8) + col) * LQ + tok) = ed;
        *(f32x4*)(Eh_t + ((b << 8) + col) * LQ + tok) = eh;
    }
    gridbar(bar + 1, 256);

    // ---------------- P3: masked channel-softmax attention ----------------
    // wave-pair q handles bh = blk*4+q; wset 0 -> w {0,3}, wset 1 -> w {1,2} (640 j/wave uniform)
    {
        const int q = wid >> 1, wset = wid & 1;
        const int bhq = blockIdx.x * 4 + q;
        if (wset == 0) {   // one wave of the pair stages
            const int j0 = lane * 4;
            *(float4*)&EdL[q][j0] = *(const float4*)(Ed_t + bhq * LQ + j0);
            bf16x4 rv = *(const bf16x4*)(rep_t + bhq * LQ + j0);
            RpL[q][j0 + 0] = (float)rv[0]; RpL[q][j0 + 1] = (float)rv[1];
            RpL[q][j0 + 2] = (float)rv[2]; RpL[q][j0 + 3] = (float)rv[3];
        }
        __syncthreads();
        const int bv = bhq >> 8, h = bhq & 255;
        const float A1 = -14.4269504f;             // -2C*log2(e)
        #pragma unroll
        for (int t = 0; t < 2; ++t) {
            const int w = wset ? (t ? 2 : 1) : (t ? 3 : 0);
            const int i = w * 64 + lane;
            const float Eh = Eh_t[bhq * LQ + i];
            float s = 0.f, acc = 0.f;
            for (int jb = 248; jb >= w * 64; jb -= 8) {
                #pragma unroll
                for (int u = 0; u < 8; ++u) {
                    const int j = jb + u;
                    float r = __builtin_amdgcn_rcpf(fmaf(EdL[q][j], Eh, 1.f));
                    float e = __builtin_amdgcn_exp2f(A1 * r);
                    e = (j > i) ? e : 0.f;
                    s += e;
                    acc = fmaf(e, RpL[q][j], acc);
                }
            }
            attn_bf[((bv << 8) + i) * DH + h] = (__bf16)(acc / (s + 1e-20f));
        }
    }
    gridbar(bar + 2, 256);

    // ---------------- P4: gate = sigmoid(rep@Wf1^T + attn@Wf2^T + bf); blend; mask ----------------
    stage32h(rep_bf, r0, PA, tid);
    stage32f(Wf1, c0, PB, tid);
    stage32h(attn_bf, r0, PC, tid);
    __syncthreads();
    f32x4 acc = z4;
    if (wid < 4) {
        #pragma unroll
        for (int ks = 0; ks < 8; ++ks)
            acc = __builtin_amdgcn_mfma_f32_16x16x32_bf16(frag(PA, wr, ks, lane),
                                                          frag(PB, wc, ks, lane), acc, 0, 0, 0);
    }
    __syncthreads();
    stage32f(Wf2, c0, PB, tid);
    __syncthreads();
    if (wid < 4) {
        #pragma unroll
        for (int ks = 0; ks < 8; ++ks)
            acc = __builtin_amdgcn_mfma_f32_16x16x32_bf16(frag(PC, wr, ks, lane),
                                                          frag(PB, wc, ks, lane), acc, 0, 0, 0);
        const float bb = bfv[col];
        #pragma unroll
        for (int r = 0; r < 4; ++r) {
            const int rr = row + r;
            float z = acc[r] + bb;
            float g = 1.f / (1.f + __expf(-z));
            float rv = (float)rep_bf[rr * DH + col];
            float av = (float)attn_bf[rr * DH + col];
            out[rr * DH + col] = (g * rv + (1.f - g) * av) * rmask[rr];
        }
    }
}

extern "C" void kernel_launch(void* const* d_in, const int* in_sizes, int n_in,
                              void* d_out, int out_size, void* d_ws, size_t ws_size,
                              hipStream_t stream) {
    const float* x    = (const float*)d_in[0];
    const float* rmsk = (const float*)d_in[1];
    const float* fc_w = (const float*)d_in[2];
    const float* fc_b = (const float*)d_in[3];
    const float* w1   = (const float*)d_in[4];
    const float* w2   = (const float*)d_in[5];
    const float* b1   = (const float*)d_in[6];
    const float* wf1  = (const float*)d_in[7];
    const float* wf2  = (const float*)d_in[8];
    const float* bfb  = (const float*)d_in[9];

    char* ws = (char*)d_ws;
    __bf16*   rep_bf  = (__bf16*)(ws);                    // 512 KB
    __bf16*   rep_t   = (__bf16*)(ws + (1u << 19));       // 512 KB
    __bf16*   attn_bf = (__bf16*)(ws + (2u << 19));       // 512 KB
    float*    Ed_t    = (float*)(ws + (3u << 19));        // 1 MB
    float*    Eh_t    = (float*)(ws + (5u << 19));        // 1 MB
    unsigned* bar     = (unsigned*)(ws + (7u << 19));

    k_zero<<<dim3(1), dim3(64), 0, stream>>>(bar);
    k_fused<<<dim3(256), dim3(512), 0, stream>>>(
        x, rmsk, fc_w, fc_b, w1, w2, b1, wf1, wf2, bfb,
        rep_bf, rep_t, attn_bf, Ed_t, Eh_t, (float*)d_out, bar);
}

// Round 8
// 31.812 us; speedup vs baseline: 8.8109x; 8.8109x over previous
//
#include <hip/hip_runtime.h>

#define DH 256
#define LQ 256

typedef __bf16 bf16x8 __attribute__((ext_vector_type(8)));
typedef __bf16 bf16x4 __attribute__((ext_vector_type(4)));
typedef __bf16 bf16x2 __attribute__((ext_vector_type(2)));
typedef float  f32x4  __attribute__((ext_vector_type(4)));

// ---- stage a 32-row x 256-col panel from f32 row-major global into LDS bf16 [32][264]
__device__ __forceinline__ void stage32f(const float* __restrict__ src, int row0,
                                         __bf16 (*dst)[264], int tid) {
    const int r = tid >> 3;
    #pragma unroll
    for (int c = 0; c < 4; ++c) {
        const int ch = (tid & 7) + 8 * c;            // 32 chunks of 8 floats per row
        const float* p = src + (row0 + r) * DH + ch * 8;
        float4 a = *(const float4*)p;
        float4 b = *(const float4*)(p + 4);
        bf16x8 v;
        v[0] = (__bf16)a.x; v[1] = (__bf16)a.y; v[2] = (__bf16)a.z; v[3] = (__bf16)a.w;
        v[4] = (__bf16)b.x; v[5] = (__bf16)b.y; v[6] = (__bf16)b.z; v[7] = (__bf16)b.w;
        *(bf16x8*)&dst[r][ch * 8] = v;
    }
}
// ---- same but bf16 source
__device__ __forceinline__ void stage32h(const __bf16* __restrict__ src, int row0,
                                         __bf16 (*dst)[264], int tid) {
    const int r = tid >> 3;
    #pragma unroll
    for (int c = 0; c < 4; ++c) {
        const int ch = (tid & 7) + 8 * c;
        *(bf16x8*)&dst[r][ch * 8] = *(const bf16x8*)&src[(row0 + r) * DH + ch * 8];
    }
}
// ---- MFMA 16x16x32 fragment from LDS panel: lane -> row r0+(l&15), k = ks*32+(l>>4)*8
__device__ __forceinline__ bf16x8 frag(const __bf16 (*m)[264], int r0, int ks, int lane) {
    return *(const bf16x8*)&m[r0 + (lane & 15)][ks * 32 + ((lane >> 4) << 3)];
}

// ---------- K1: rep = elu(X @ Wfc^T + b) -> rep_bf (row-major) + rep_t (bh-major) ----------
__global__ __launch_bounds__(256) void k_fc(
    const float* __restrict__ X, const float* __restrict__ Wfc, const float* __restrict__ bfc,
    __bf16* __restrict__ rep_bf, __bf16* __restrict__ rep_t)
{
    __shared__ __bf16 Xa[32][264];
    __shared__ __bf16 Wb[32][264];
    const int tid = threadIdx.x, lane = tid & 63, wid = tid >> 6;
    const int mb = blockIdx.x >> 3, nb = blockIdx.x & 7;
    const int r0 = mb * 32, c0 = nb * 32;
    stage32f(X, r0, Xa, tid);
    stage32f(Wfc, c0, Wb, tid);
    __syncthreads();
    const int wr = (wid >> 1) * 16, wc = (wid & 1) * 16;
    f32x4 acc = {0.f, 0.f, 0.f, 0.f};
    #pragma unroll
    for (int ks = 0; ks < 8; ++ks)
        acc = __builtin_amdgcn_mfma_f32_16x16x32_bf16(frag(Xa, wr, ks, lane),
                                                      frag(Wb, wc, ks, lane), acc, 0, 0, 0);
    const int col = c0 + wc + (lane & 15);
    const int row = r0 + wr + ((lane >> 4) << 2);
    const int b = row >> 8, tok = row & 255;
    const float bv = bfc[col];
    bf16x4 pk;
    #pragma unroll
    for (int r = 0; r < 4; ++r) {
        float v = acc[r] + bv;
        v = (v > 0.f) ? v : (__expf(v) - 1.f);
        __bf16 h = (__bf16)v;
        rep_bf[(row + r) * DH + col] = h;
        pk[r] = h;
    }
    *(bf16x4*)(rep_t + ((b << 8) + col) * LQ + tok) = pk;
}

// ---------- K2: Ed = exp(0.4*(rep@W1^T+b1)), Eh = exp(0.4*rep@W2^T)  (bh-major f32) ----------
__global__ __launch_bounds__(256) void k_dephead(
    const __bf16* __restrict__ rep_bf, const float* __restrict__ W1, const float* __restrict__ W2,
    const float* __restrict__ b1, float* __restrict__ Ed_t, float* __restrict__ Eh_t)
{
    __shared__ __bf16 Ra[32][264];
    __shared__ __bf16 U1[32][264];
    __shared__ __bf16 U2[32][264];
    const int tid = threadIdx.x, lane = tid & 63, wid = tid >> 6;
    const int mb = blockIdx.x >> 3, nb = blockIdx.x & 7;
    const int r0 = mb * 32, c0 = nb * 32;
    stage32h(rep_bf, r0, Ra, tid);
    stage32f(W1, c0, U1, tid);
    stage32f(W2, c0, U2, tid);
    __syncthreads();
    const int wr = (wid >> 1) * 16, wc = (wid & 1) * 16;
    f32x4 ad = {0.f, 0.f, 0.f, 0.f}, ah = {0.f, 0.f, 0.f, 0.f};
    #pragma unroll
    for (int ks = 0; ks < 8; ++ks) {
        bf16x8 a = frag(Ra, wr, ks, lane);
        ad = __builtin_amdgcn_mfma_f32_16x16x32_bf16(a, frag(U1, wc, ks, lane), ad, 0, 0, 0);
        ah = __builtin_amdgcn_mfma_f32_16x16x32_bf16(a, frag(U2, wc, ks, lane), ah, 0, 0, 0);
    }
    const int col = c0 + wc + (lane & 15);
    const int row = r0 + wr + ((lane >> 4) << 2);
    const int b = row >> 8, tok = row & 255;
    const float bb = b1[col];
    f32x4 ed, eh;
    #pragma unroll
    for (int r = 0; r < 4; ++r) {
        ed[r] = __expf(0.4f * (ad[r] + bb));   // 2/C = 0.4
        eh[r] = __expf(0.4f * ah[r]);
    }
    *(f32x4*)(Ed_t + ((b << 8) + col) * LQ + tok) = ed;
    *(f32x4*)(Eh_t + ((b << 8) + col) * LQ + tok) = eh;
}

// ---------- K3: per-(b,h) masked channel-softmax; w_ij = exp2(A1*rcp(Ed_j*Eh_i+1)) ----------
// block = one bh (1024 blocks x 128 thr). wave0 -> w {0,3}, wave1 -> w {1,2}: 320 j/wave.
// Loop split: j >= (w+1)*64 is always > i (no mask); only the last 64 j's need the mask.
__global__ __launch_bounds__(128) void k_attn(
    const float* __restrict__ Ed_t, const float* __restrict__ Eh_t,
    const __bf16* __restrict__ rep_t, __bf16* __restrict__ attn_bf)
{
    __shared__ float Ed[256];
    __shared__ float Rp[256];
    const int bh = blockIdx.x;
    const int tid = threadIdx.x, lane = tid & 63, wv = tid >> 6;
    {   // stage once per bh: 128 threads x 2 elems
        const int j0 = tid * 2;
        float2 d = *(const float2*)(Ed_t + bh * LQ + j0);
        bf16x2 rv = *(const bf16x2*)(rep_t + bh * LQ + j0);
        Ed[j0] = d.x; Ed[j0 + 1] = d.y;
        Rp[j0] = (float)rv[0]; Rp[j0 + 1] = (float)rv[1];
    }
    __syncthreads();
    const int bv = bh >> 8, h = bh & 255;
    const float A1 = -14.4269504f;             // -2C*log2(e)
    #pragma unroll
    for (int t = 0; t < 2; ++t) {
        const int w = wv ? (t ? 2 : 1) : (t ? 3 : 0);
        const int i = w * 64 + lane;
        const float Eh = Eh_t[bh * LQ + i];
        float s = 0.f, acc = 0.f;
        // unmasked region: jb from 248 down to (w+1)*64
        for (int jb = 248; jb >= (w + 1) * 64; jb -= 8) {
            #pragma unroll
            for (int u = 0; u < 8; ++u) {
                const int j = jb + u;
                float r = __builtin_amdgcn_rcpf(fmaf(Ed[j], Eh, 1.f));
                float e = __builtin_amdgcn_exp2f(A1 * r);
                s += e;
                acc = fmaf(e, Rp[j], acc);
            }
        }
        // masked region: jb in [w*64, w*64+56]
        for (int jb = w * 64 + 56; jb >= w * 64; jb -= 8) {
            #pragma unroll
            for (int u = 0; u < 8; ++u) {
                const int j = jb + u;
                float r = __builtin_amdgcn_rcpf(fmaf(Ed[j], Eh, 1.f));
                float e = __builtin_amdgcn_exp2f(A1 * r);
                e = (j > i) ? e : 0.f;
                s += e;
                acc = fmaf(e, Rp[j], acc);
            }
        }
        attn_bf[((bv << 8) + i) * DH + h] = (__bf16)(acc / (s + 1e-20f));
    }
}

// ---------- K4: gate = sigmoid(rep@Wf1^T + attn@Wf2^T + bf); blend; mask ----------
__global__ __launch_bounds__(256) void k_gate(
    const __bf16* __restrict__ rep_bf, const __bf16* __restrict__ attn_bf,
    const float* __restrict__ Wf1, const float* __restrict__ Wf2,
    const float* __restrict__ bfv, const float* __restrict__ rmask,
    float* __restrict__ out)
{
    __shared__ __bf16 Ra[32][264];
    __shared__ __bf16 Aa[32][264];
    __shared__ __bf16 U1[32][264];
    __shared__ __bf16 U2[32][264];
    const int tid = threadIdx.x, lane = tid & 63, wid = tid >> 6;
    const int mb = blockIdx.x >> 3, nb = blockIdx.x & 7;
    const int r0 = mb * 32, c0 = nb * 32;
    stage32h(rep_bf, r0, Ra, tid);
    stage32h(attn_bf, r0, Aa, tid);
    stage32f(Wf1, c0, U1, tid);
    stage32f(Wf2, c0, U2, tid);
    __syncthreads();
    const int wr = (wid >> 1) * 16, wc = (wid & 1) * 16;
    f32x4 acc = {0.f, 0.f, 0.f, 0.f};
    #pragma unroll
    for (int ks = 0; ks < 8; ++ks) {
        acc = __builtin_amdgcn_mfma_f32_16x16x32_bf16(frag(Ra, wr, ks, lane),
                                                      frag(U1, wc, ks, lane), acc, 0, 0, 0);
        acc = __builtin_amdgcn_mfma_f32_16x16x32_bf16(frag(Aa, wr, ks, lane),
                                                      frag(U2, wc, ks, lane), acc, 0, 0, 0);
    }
    const int col = c0 + wc + (lane & 15);
    const int row = r0 + wr + ((lane >> 4) << 2);
    const float bb = bfv[col];
    #pragma unroll
    for (int r = 0; r < 4; ++r) {
        const int rr = row + r;
        float z = acc[r] + bb;
        float g = 1.f / (1.f + __expf(-z));
        float rv = (float)rep_bf[rr * DH + col];
        float av = (float)attn_bf[rr * DH + col];
        out[rr * DH + col] = (g * rv + (1.f - g) * av) * rmask[rr];
    }
}

extern "C" void kernel_launch(void* const* d_in, const int* in_sizes, int n_in,
                              void* d_out, int out_size, void* d_ws, size_t ws_size,
                              hipStream_t stream) {
    const float* x    = (const float*)d_in[0];
    const float* rmsk = (const float*)d_in[1];
    const float* fc_w = (const float*)d_in[2];
    const float* fc_b = (const float*)d_in[3];
    const float* w1   = (const float*)d_in[4];
    const float* w2   = (const float*)d_in[5];
    const float* b1   = (const float*)d_in[6];
    const float* wf1  = (const float*)d_in[7];
    const float* wf2  = (const float*)d_in[8];
    const float* bfb  = (const float*)d_in[9];

    char* ws = (char*)d_ws;
    __bf16* rep_bf  = (__bf16*)(ws);                  // 512 KB row-major
    __bf16* rep_t   = (__bf16*)(ws + (1u << 19));     // 512 KB bh-major
    __bf16* attn_bf = (__bf16*)(ws + (2u << 19));     // 512 KB row-major
    float*  Ed_t    = (float*)(ws + (3u << 19));      // 1 MB bh-major
    float*  Eh_t    = (float*)(ws + (5u << 19));      // 1 MB bh-major

    k_fc<<<dim3(256), dim3(256), 0, stream>>>(x, fc_w, fc_b, rep_bf, rep_t);
    k_dephead<<<dim3(256), dim3(256), 0, stream>>>(rep_bf, w1, w2, b1, Ed_t, Eh_t);
    k_attn<<<dim3(1024), dim3(128), 0, stream>>>(Ed_t, Eh_t, rep_t, attn_bf);
    k_gate<<<dim3(256), dim3(256), 0, stream>>>(rep_bf, attn_bf, wf1, wf2, bfb, rmsk,
                                                (float*)d_out);
}

// Round 10
// 31.211 us; speedup vs baseline: 8.9805x; 1.0192x over previous
//
#include <hip/hip_runtime.h>

#define DH 256
#define LQ 256

typedef __bf16 bf16x8 __attribute__((ext_vector_type(8)));
typedef __bf16 bf16x4 __attribute__((ext_vector_type(4)));
typedef __bf16 bf16x2 __attribute__((ext_vector_type(2)));
typedef float  f32x4  __attribute__((ext_vector_type(4)));

// ---- stage a 32-row x 256-col panel from f32 row-major global into LDS bf16 [32][264]
__device__ __forceinline__ void stage32f(const float* __restrict__ src, int row0,
                                         __bf16 (*dst)[264], int tid) {
    const int r = tid >> 3;
    #pragma unroll
    for (int c = 0; c < 4; ++c) {
        const int ch = (tid & 7) + 8 * c;
        const float* p = src + (row0 + r) * DH + ch * 8;
        float4 a = *(const float4*)p;
        float4 b = *(const float4*)(p + 4);
        bf16x8 v;
        v[0] = (__bf16)a.x; v[1] = (__bf16)a.y; v[2] = (__bf16)a.z; v[3] = (__bf16)a.w;
        v[4] = (__bf16)b.x; v[5] = (__bf16)b.y; v[6] = (__bf16)b.z; v[7] = (__bf16)b.w;
        *(bf16x8*)&dst[r][ch * 8] = v;
    }
}
// ---- same but bf16 source
__device__ __forceinline__ void stage32h(const __bf16* __restrict__ src, int row0,
                                         __bf16 (*dst)[264], int tid) {
    const int r = tid >> 3;
    #pragma unroll
    for (int c = 0; c < 4; ++c) {
        const int ch = (tid & 7) + 8 * c;
        *(bf16x8*)&dst[r][ch * 8] = *(const bf16x8*)&src[(row0 + r) * DH + ch * 8];
    }
}
// ---- transposed stage: dst[tok_local][h] <- src[(b*256+h)*256 + tok0+tok_local], h = tid
__device__ __forceinline__ void stageT(const __bf16* __restrict__ src, int b, int tok0,
                                       __bf16 (*dst)[264], int tid) {
    const __bf16* p = src + (((b << 8) + tid) << 8) + tok0;
    bf16x8 v0 = *(const bf16x8*)(p);
    bf16x8 v1 = *(const bf16x8*)(p + 8);
    bf16x8 v2 = *(const bf16x8*)(p + 16);
    bf16x8 v3 = *(const bf16x8*)(p + 24);
    #pragma unroll
    for (int t = 0; t < 8; ++t) {
        dst[t][tid]      = v0[t];
        dst[8 + t][tid]  = v1[t];
        dst[16 + t][tid] = v2[t];
        dst[24 + t][tid] = v3[t];
    }
}
// ---- MFMA 16x16x32 fragment from LDS panel
__device__ __forceinline__ bf16x8 frag(const __bf16 (*m)[264], int r0, int ks, int lane) {
    return *(const bf16x8*)&m[r0 + (lane & 15)][ks * 32 + ((lane >> 4) << 3)];
}

// ---------- K1: rep = elu(X @ Wfc^T + b) -> rep_bf (row-major) + rep_t (bh-major) ----------
__global__ __launch_bounds__(256) void k_fc(
    const float* __restrict__ X, const float* __restrict__ Wfc, const float* __restrict__ bfc,
    __bf16* __restrict__ rep_bf, __bf16* __restrict__ rep_t)
{
    __shared__ __bf16 Xa[32][264];
    __shared__ __bf16 Wb[32][264];
    const int tid = threadIdx.x, lane = tid & 63, wid = tid >> 6;
    const int mb = blockIdx.x >> 3, nb = blockIdx.x & 7;
    const int r0 = mb * 32, c0 = nb * 32;
    stage32f(X, r0, Xa, tid);
    stage32f(Wfc, c0, Wb, tid);
    __syncthreads();
    const int wr = (wid >> 1) * 16, wc = (wid & 1) * 16;
    f32x4 acc = {0.f, 0.f, 0.f, 0.f};
    #pragma unroll
    for (int ks = 0; ks < 8; ++ks)
        acc = __builtin_amdgcn_mfma_f32_16x16x32_bf16(frag(Xa, wr, ks, lane),
                                                      frag(Wb, wc, ks, lane), acc, 0, 0, 0);
    const int col = c0 + wc + (lane & 15);
    const int row = r0 + wr + ((lane >> 4) << 2);
    const int b = row >> 8, tok = row & 255;
    const float bv = bfc[col];
    bf16x4 pk;
    #pragma unroll
    for (int r = 0; r < 4; ++r) {
        float v = acc[r] + bv;
        v = (v > 0.f) ? v : (__expf(v) - 1.f);
        __bf16 h = (__bf16)v;
        rep_bf[(row + r) * DH + col] = h;
        pk[r] = h;
    }
    *(bf16x4*)(rep_t + ((b << 8) + col) * LQ + tok) = pk;
}

// ---------- K2: Ed = exp(0.4*(rep@W1^T+b1)), Eh = exp(0.4*rep@W2^T)  (bh-major f32) ----------
__global__ __launch_bounds__(256) void k_dephead(
    const __bf16* __restrict__ rep_bf, const float* __restrict__ W1, const float* __restrict__ W2,
    const float* __restrict__ b1, float* __restrict__ Ed_t, float* __restrict__ Eh_t)
{
    __shared__ __bf16 Ra[32][264];
    __shared__ __bf16 U1[32][264];
    __shared__ __bf16 U2[32][264];
    const int tid = threadIdx.x, lane = tid & 63, wid = tid >> 6;
    const int mb = blockIdx.x >> 3, nb = blockIdx.x & 7;
    const int r0 = mb * 32, c0 = nb * 32;
    stage32h(rep_bf, r0, Ra, tid);
    stage32f(W1, c0, U1, tid);
    stage32f(W2, c0, U2, tid);
    __syncthreads();
    const int wr = (wid >> 1) * 16, wc = (wid & 1) * 16;
    f32x4 ad = {0.f, 0.f, 0.f, 0.f}, ah = {0.f, 0.f, 0.f, 0.f};
    #pragma unroll
    for (int ks = 0; ks < 8; ++ks) {
        bf16x8 a = frag(Ra, wr, ks, lane);
        ad = __builtin_amdgcn_mfma_f32_16x16x32_bf16(a, frag(U1, wc, ks, lane), ad, 0, 0, 0);
        ah = __builtin_amdgcn_mfma_f32_16x16x32_bf16(a, frag(U2, wc, ks, lane), ah, 0, 0, 0);
    }
    const int col = c0 + wc + (lane & 15);
    const int row = r0 + wr + ((lane >> 4) << 2);
    const int b = row >> 8, tok = row & 255;
    const float bb = b1[col];
    f32x4 ed, eh;
    #pragma unroll
    for (int r = 0; r < 4; ++r) {
        ed[r] = __expf(0.4f * (ad[r] + bb));   // 2/C = 0.4
        eh[r] = __expf(0.4f * ah[r]);
    }
    *(f32x4*)(Ed_t + ((b << 8) + col) * LQ + tok) = ed;
    *(f32x4*)(Eh_t + ((b << 8) + col) * LQ + tok) = eh;
}

// ---------- K3: per-(b,h) masked channel-softmax; w_ij = exp2(A1*rcp(Ed_j*Eh_i+1)) ----------
// block = one bh (1024 x 128 thr). wave0 -> w {0,3}, wave1 -> w {1,2}: 320 j/wave uniform.
// Scalar inner loop (round-8 proven); output bh-major (contiguous per-wave stores).
__global__ __launch_bounds__(128) void k_attn(
    const float* __restrict__ Ed_t, const float* __restrict__ Eh_t,
    const __bf16* __restrict__ rep_t, __bf16* __restrict__ attn_t)
{
    __shared__ float Ed[256];
    __shared__ float Rp[256];
    const int bh = blockIdx.x;
    const int tid = threadIdx.x, lane = tid & 63, wv = tid >> 6;
    {   // stage once per bh: 128 threads x 2 elems
        const int j0 = tid * 2;
        float2 d = *(const float2*)(Ed_t + bh * LQ + j0);
        bf16x2 rv = *(const bf16x2*)(rep_t + bh * LQ + j0);
        Ed[j0] = d.x; Ed[j0 + 1] = d.y;
        Rp[j0] = (float)rv[0]; Rp[j0 + 1] = (float)rv[1];
    }
    __syncthreads();
    const float A1 = -14.4269504f;             // -2C*log2(e)
    #pragma unroll
    for (int t = 0; t < 2; ++t) {
        const int w = wv ? (t ? 2 : 1) : (t ? 3 : 0);
        const int i = w * 64 + lane;
        const float Eh = Eh_t[bh * LQ + i];
        float s = 0.f, acc = 0.f;
        // unmasked region: j in [(w+1)*64, 256) -- always j > i
        for (int jb = 248; jb >= (w + 1) * 64; jb -= 8) {
            #pragma unroll
            for (int u = 0; u < 8; ++u) {
                const int j = jb + u;
                float r = __builtin_amdgcn_rcpf(fmaf(Ed[j], Eh, 1.f));
                float e = __builtin_amdgcn_exp2f(A1 * r);
                s += e;
                acc = fmaf(e, Rp[j], acc);
            }
        }
        // masked region: j in [w*64, w*64+64)
        for (int jb = w * 64 + 56; jb >= w * 64; jb -= 8) {
            #pragma unroll
            for (int u = 0; u < 8; ++u) {
                const int j = jb + u;
                float r = __builtin_amdgcn_rcpf(fmaf(Ed[j], Eh, 1.f));
                float e = __builtin_amdgcn_exp2f(A1 * r);
                e = (j > i) ? e : 0.f;
                s += e;
                acc = fmaf(e, Rp[j], acc);
            }
        }
        attn_t[bh * LQ + i] = (__bf16)(acc / (s + 1e-20f));   // contiguous per wave
    }
}

// ---------- K4: gate = sigmoid(rep@Wf1^T + attn@Wf2^T + bf); blend; mask ----------
__global__ __launch_bounds__(256) void k_gate(
    const __bf16* __restrict__ rep_bf, const __bf16* __restrict__ attn_t,
    const float* __restrict__ Wf1, const float* __restrict__ Wf2,
    const float* __restrict__ bfv, const float* __restrict__ rmask,
    float* __restrict__ out)
{
    __shared__ __bf16 Ra[32][264];
    __shared__ __bf16 Aa[32][264];
    __shared__ __bf16 U1[32][264];
    __shared__ __bf16 U2[32][264];
    const int tid = threadIdx.x, lane = tid & 63, wid = tid >> 6;
    const int mb = blockIdx.x >> 3, nb = blockIdx.x & 7;
    const int r0 = mb * 32, c0 = nb * 32;
    const int b = r0 >> 8, tok0 = r0 & 255;
    stage32h(rep_bf, r0, Ra, tid);
    stageT(attn_t, b, tok0, Aa, tid);
    stage32f(Wf1, c0, U1, tid);
    stage32f(Wf2, c0, U2, tid);
    __syncthreads();
    const int wr = (wid >> 1) * 16, wc = (wid & 1) * 16;
    f32x4 acc = {0.f, 0.f, 0.f, 0.f};
    #pragma unroll
    for (int ks = 0; ks < 8; ++ks) {
        acc = __builtin_amdgcn_mfma_f32_16x16x32_bf16(frag(Ra, wr, ks, lane),
                                                      frag(U1, wc, ks, lane), acc, 0, 0, 0);
        acc = __builtin_amdgcn_mfma_f32_16x16x32_bf16(frag(Aa, wr, ks, lane),
                                                      frag(U2, wc, ks, lane), acc, 0, 0, 0);
    }
    const int col = c0 + wc + (lane & 15);
    const int lr0 = wr + ((lane >> 4) << 2);     // block-local row
    const float bb = bfv[col];
    #pragma unroll
    for (int r = 0; r < 4; ++r) {
        const int lr = lr0 + r, rr = r0 + lr;
        float z = acc[r] + bb;
        float g = 1.f / (1.f + __expf(-z));
        float rv = (float)Ra[lr][col];
        float av = (float)Aa[lr][col];
        out[rr * DH + col] = (g * rv + (1.f - g) * av) * rmask[rr];
    }
}

extern "C" void kernel_launch(void* const* d_in, const int* in_sizes, int n_in,
                              void* d_out, int out_size, void* d_ws, size_t ws_size,
                              hipStream_t stream) {
    const float* x    = (const float*)d_in[0];
    const float* rmsk = (const float*)d_in[1];
    const float* fc_w = (const float*)d_in[2];
    const float* fc_b = (const float*)d_in[3];
    const float* w1   = (const float*)d_in[4];
    const float* w2   = (const float*)d_in[5];
    const float* b1   = (const float*)d_in[6];
    const float* wf1  = (const float*)d_in[7];
    const float* wf2  = (const float*)d_in[8];
    const float* bfb  = (const float*)d_in[9];

    char* ws = (char*)d_ws;
    __bf16* rep_bf  = (__bf16*)(ws);                  // 512 KB row-major
    __bf16* rep_t   = (__bf16*)(ws + (1u << 19));     // 512 KB bh-major
    __bf16* attn_t  = (__bf16*)(ws + (2u << 19));     // 512 KB bh-major
    float*  Ed_t    = (float*)(ws + (3u << 19));      // 1 MB bh-major
    float*  Eh_t    = (float*)(ws + (5u << 19));      // 1 MB bh-major

    k_fc<<<dim3(256), dim3(256), 0, stream>>>(x, fc_w, fc_b, rep_bf, rep_t);
    k_dephead<<<dim3(256), dim3(256), 0, stream>>>(rep_bf, w1, w2, b1, Ed_t, Eh_t);
    k_attn<<<dim3(1024), dim3(128), 0, stream>>>(Ed_t, Eh_t, rep_t, attn_t);
    k_gate<<<dim3(256), dim3(256), 0, stream>>>(rep_bf, attn_t, wf1, wf2, bfb, rmsk,
                                                (float*)d_out);
}